// Round 4
// baseline (491400.684 us; speedup 1.0000x reference)
//
#include <hip/hip_runtime.h>
#include <hip/hip_bf16.h>
#include <stdint.h>

// ESN: out[t] = tanh(U[t] + W_res @ s_{t-1}), T=16384 sequential steps.
// Kernel 1: U = X@W_in^T into d_out in place.
// Kernel 2: 16 worker blocks claimed on ONE XCD (XCC_ID pigeonhole over 128
// blocks). Barrier-free dataflow: each thread polls its own 12 column slots
// (tag<<32|value, 8B) from a depth-16 ring. Producers publish with AGENT-scope
// stores (LLC-visible, round-2-proven). Consumers: adaptive two-phase poll —
// fast sc0 batch (XCD-L2) with fallback to agent-scope batch; a one-shot sc0
// recheck after any fallback decides late-vs-blind and disables the fast path
// permanently if blind. All failure modes degrade to the correct agent path.

constexpr int T_N = 16384;
constexpr int R_N = 1024;
constexpr int I_N = 128;

// ---------------------------------------------------------------- kernel 1
constexpr int BT = 64, BR = 64;

__global__ __launch_bounds__(256) void gemm_u_kernel(
    const float* __restrict__ X, const float* __restrict__ Win,
    float* __restrict__ U)
{
    __shared__ float XS[BT][68];
    __shared__ float WS[BR][68];
    const int tid = threadIdx.x;
    const int ty = tid >> 4, tx = tid & 15;
    const int t0 = blockIdx.x * BT;
    const int r0 = blockIdx.y * BR;
    float acc[4][4] = {};

    for (int k0 = 0; k0 < I_N; k0 += 64) {
        for (int idx = tid; idx < BT * 16; idx += 256) {
            int row = idx >> 4, c4 = (idx & 15) << 2;
            *reinterpret_cast<float4*>(&XS[row][c4]) =
                *reinterpret_cast<const float4*>(&X[(size_t)(t0 + row) * I_N + k0 + c4]);
        }
        for (int idx = tid; idx < BR * 16; idx += 256) {
            int row = idx >> 4, c4 = (idx & 15) << 2;
            *reinterpret_cast<float4*>(&WS[row][c4]) =
                *reinterpret_cast<const float4*>(&Win[(size_t)(r0 + row) * I_N + k0 + c4]);
        }
        __syncthreads();
#pragma unroll
        for (int k = 0; k < 64; k += 4) {
            float4 a[4], b[4];
#pragma unroll
            for (int i = 0; i < 4; ++i)
                a[i] = *reinterpret_cast<const float4*>(&XS[ty + 16 * i][k]);
#pragma unroll
            for (int jj = 0; jj < 4; ++jj)
                b[jj] = *reinterpret_cast<const float4*>(&WS[tx + 16 * jj][k]);
#pragma unroll
            for (int i = 0; i < 4; ++i)
#pragma unroll
                for (int jj = 0; jj < 4; ++jj)
                    acc[i][jj] += a[i].x * b[jj].x + a[i].y * b[jj].y +
                                  a[i].z * b[jj].z + a[i].w * b[jj].w;
        }
        __syncthreads();
    }
#pragma unroll
    for (int i = 0; i < 4; ++i)
#pragma unroll
        for (int jj = 0; jj < 4; ++jj)
            U[(size_t)(t0 + ty + 16 * i) * R_N + (r0 + tx + 16 * jj)] = acc[i][jj];
}

// ---------------------------------------------------------------- kernel 2
constexpr int GBLK    = 16;            // worker blocks (one XCD)
constexpr int NLAUNCH = 128;           // launched; pigeonhole: some XCD gets 16
constexpr int B2      = 512;           // 8 waves
constexpr int RPB     = R_N / GBLK;    // 64 rows per block
constexpr int TPR     = 8;             // threads per row
constexpr int KMAX    = 96;            // nnz/row cap (validated r1/r2)
constexpr int NSL     = KMAX / TPR;    // 12 register slots per thread
constexpr int DEPTH   = 16;            // ring depth (proof needs ~8; slack)
constexpr int FASTCAP = 64;            // sc0 rounds before falling back
constexpr int SLOWCAP = 4096;          // agent rounds before declaring wedge

typedef unsigned long long ull;

__device__ __forceinline__ float fast_tanh(float x) {
    float ax = fabsf(x);
    float e  = __expf(-2.0f * ax);
    float y  = (1.0f - e) / (1.0f + e);
    return copysignf(y, x);
}

__device__ __forceinline__ uint32_t tag_of(ull v) { return (uint32_t)(v >> 32); }

// batch 12 sc0 (L1-bypass, L2-served if semantics hold) loads + single wait
__device__ __forceinline__ uint32_t poll_sc0(const ull* base, const int* cols,
                                             ull* w) {
    asm volatile(
        "global_load_dwordx2 %0, %12, off sc0\n\t"
        "global_load_dwordx2 %1, %13, off sc0\n\t"
        "global_load_dwordx2 %2, %14, off sc0\n\t"
        "global_load_dwordx2 %3, %15, off sc0\n\t"
        "global_load_dwordx2 %4, %16, off sc0\n\t"
        "global_load_dwordx2 %5, %17, off sc0\n\t"
        "global_load_dwordx2 %6, %18, off sc0\n\t"
        "global_load_dwordx2 %7, %19, off sc0\n\t"
        "global_load_dwordx2 %8, %20, off sc0\n\t"
        "global_load_dwordx2 %9, %21, off sc0\n\t"
        "global_load_dwordx2 %10, %22, off sc0\n\t"
        "global_load_dwordx2 %11, %23, off sc0\n\t"
        "s_waitcnt vmcnt(0)"
        : "=&v"(w[0]), "=&v"(w[1]), "=&v"(w[2]), "=&v"(w[3]),
          "=&v"(w[4]), "=&v"(w[5]), "=&v"(w[6]), "=&v"(w[7]),
          "=&v"(w[8]), "=&v"(w[9]), "=&v"(w[10]), "=&v"(w[11])
        : "v"(base + cols[0]), "v"(base + cols[1]),
          "v"(base + cols[2]), "v"(base + cols[3]),
          "v"(base + cols[4]), "v"(base + cols[5]),
          "v"(base + cols[6]), "v"(base + cols[7]),
          "v"(base + cols[8]), "v"(base + cols[9]),
          "v"(base + cols[10]), "v"(base + cols[11])
        : "memory");
    uint32_t mn = tag_of(w[0]);
#pragma unroll
    for (int k = 1; k < NSL; ++k) { uint32_t x = tag_of(w[k]); mn = mn < x ? mn : x; }
    return mn;
}

// batch 12 agent-scope loads (LLC, round-2-proven visibility)
__device__ __forceinline__ uint32_t poll_agent(const ull* base, const int* cols,
                                               ull* w) {
#pragma unroll
    for (int k = 0; k < NSL; ++k)
        w[k] = __hip_atomic_load(base + cols[k], __ATOMIC_RELAXED,
                                 __HIP_MEMORY_SCOPE_AGENT);
    uint32_t mn = tag_of(w[0]);
#pragma unroll
    for (int k = 1; k < NSL; ++k) { uint32_t x = tag_of(w[k]); mn = mn < x ? mn : x; }
    return mn;
}

__global__ __launch_bounds__(512) void esn_scan_kernel(
    const float* __restrict__ Wres, const float* __restrict__ state0,
    float* out, uint32_t* hdr, ull* slots)
{
    __shared__ int   s_role;
    __shared__ uint2 ell[RPB][KMAX];     // 48 KB (col, val-bits)
    __shared__ int   cnt[RPB];

    const int tid = threadIdx.x;

    // ---- claim: first XCD to collect 16 blocks wins; everyone else exits
    if (tid == 0) {
        uint32_t xcd;
        asm volatile("s_getreg_b32 %0, hwreg(HW_REG_XCC_ID)" : "=s"(xcd));
        xcd &= 7u;
        uint32_t rank = __hip_atomic_fetch_add(&hdr[xcd], 1u,
                            __ATOMIC_RELAXED, __HIP_MEMORY_SCOPE_AGENT);
        int role = -1;
        if (rank < (uint32_t)GBLK) {
            if (rank == (uint32_t)(GBLK - 1)) {
                uint32_t expected = 0u;
                __hip_atomic_compare_exchange_strong(&hdr[8], &expected, xcd + 1u,
                    __ATOMIC_RELAXED, __ATOMIC_RELAXED, __HIP_MEMORY_SCOPE_AGENT);
            }
            uint32_t win = 0; int spins = 0;
            do {
                win = __hip_atomic_load(&hdr[8], __ATOMIC_RELAXED,
                                        __HIP_MEMORY_SCOPE_AGENT);
            } while (win == 0u && ++spins < (1 << 20));
            if (win == xcd + 1u) role = (int)rank;
        }
        s_role = role;
    }
    __syncthreads();
    const int b = s_role;
    if (b < 0) return;                   // not a worker: free the CU
    const int row0 = b * RPB;

    // ---- one-time: extract this block's sparse rows from dense W_res
    if (tid < RPB) cnt[tid] = 0;
    __syncthreads();
    for (int idx = tid; idx < RPB * R_N; idx += B2) {
        int r = idx >> 10, c = idx & (R_N - 1);
        float w = Wres[(size_t)(row0 + r) * R_N + c];
        if (w != 0.0f) {
            int slot = atomicAdd(&cnt[r], 1);
            if (slot < KMAX) ell[r][slot] = make_uint2((uint32_t)c, __float_as_uint(w));
        }
    }
    __syncthreads();

    // ---- hoist my slots into registers.
    // Dead slots duplicate this row's first real col (avoids a global hotspot
    // on row 0 and adds no new cross-row dependency).
    const int rloc = tid / TPR;          // 0..63
    const int j    = tid % TPR;          // 0..7
    const int row  = row0 + rloc;
    int   cols[NSL];
    float vals[NSL];
    {
        int myn = cnt[rloc];
        int c0  = (myn > 0) ? (int)ell[rloc][0].x : 0;
#pragma unroll
        for (int k = 0; k < NSL; ++k) {
            int slot = j + k * TPR;
            if (slot < myn) {
                uint2 e = ell[rloc][slot];
                cols[k] = (int)e.x;
                vals[k] = __uint_as_float(e.y);
            } else { cols[k] = c0; vals[k] = 0.0f; }
        }
    }

    float u_cur = (j == 0) ? out[row] : 0.0f;   // u_0 for my row
    bool use_fast = true;                // sc0 fast path enabled
    bool wedged   = false;               // protocol gave up (wrong-not-hang)

    // ---- barrier-free sequential scan
    for (int t = 0; t < T_N; ++t) {
        float u_next = 0.0f;
        if (j == 0 && t + 1 < T_N) u_next = out[(size_t)(t + 1) * R_N + row];

        float sv[NSL];
        if (t == 0) {
#pragma unroll
            for (int k = 0; k < NSL; ++k) sv[k] = state0[cols[k]];
        } else {
            const ull* base = slots + ((size_t)((t - 1) & (DEPTH - 1)) << 10);
            const uint32_t want = (uint32_t)t;   // s_{t-1} carries tag t
            ull w[NSL];
            bool got = false;

            if (use_fast && !wedged) {           // phase 1: XCD-local L2
                int r = 0;
                do {
                    if (poll_sc0(base, cols, w) >= want) { got = true; break; }
                } while (++r < FASTCAP);
            }
            if (!got) {                          // phase 2: agent scope (LLC)
                int rounds = 0;
                for (;;) {
                    if (poll_agent(base, cols, w) >= want) { got = true; break; }
                    if (++rounds >= (wedged ? 1 : SLOWCAP)) { wedged = true; break; }
                }
                if (use_fast && got && !wedged) {
                    // late or blind? one sc0 tag recheck decides.
                    ull rw[NSL];
                    if (poll_sc0(base, cols, rw) < want) use_fast = false;
                }
            }
#pragma unroll
            for (int k = 0; k < NSL; ++k) sv[k] = __uint_as_float((uint32_t)w[k]);
        }

        float acc = 0.0f;
#pragma unroll
        for (int k = 0; k < NSL; ++k) acc += vals[k] * sv[k];

        acc += __shfl_xor(acc, 1, TPR);
        acc += __shfl_xor(acc, 2, TPR);
        acc += __shfl_xor(acc, 4, TPR);

        if (j == 0) {
            float y = fast_tanh(u_cur + acc);
            // publish FIRST (consumers are waiting on this), answer second
            ull pkt = ((ull)(uint32_t)(t + 1) << 32) | (ull)__float_as_uint(y);
            __hip_atomic_store(&slots[((size_t)(t & (DEPTH - 1)) << 10) + row],
                               pkt, __ATOMIC_RELAXED, __HIP_MEMORY_SCOPE_AGENT);
            out[(size_t)t * R_N + row] = y;
        }
        u_cur = u_next;
    }
}

// ---------------------------------------------------------------- launcher
extern "C" void kernel_launch(void* const* d_in, const int* in_sizes, int n_in,
                              void* d_out, int out_size, void* d_ws, size_t ws_size,
                              hipStream_t stream)
{
    const float* X      = (const float*)d_in[0];   // (T, I)
    const float* W_in   = (const float*)d_in[1];   // (R, I)
    const float* W_res  = (const float*)d_in[2];   // (R, R)
    const float* state0 = (const float*)d_in[3];   // (R,)
    float* out = (float*)d_out;                    // (T, R)

    uint32_t* hdr = (uint32_t*)d_ws;                    // 64 u32 header
    ull* slots = (ull*)((char*)d_ws + 256);             // DEPTH x 1024 x 8B

    // zero header + ring tags (harness poisons ws with 0xAA each launch)
    hipMemsetAsync(d_ws, 0, 256 + (size_t)DEPTH * R_N * sizeof(ull), stream);

    dim3 g1(T_N / BT, R_N / BR);
    gemm_u_kernel<<<g1, 256, 0, stream>>>(X, W_in, out);

    esn_scan_kernel<<<NLAUNCH, B2, 0, stream>>>(W_res, state0, out, hdr, slots);
}

// Round 5
// 24269.571 us; speedup vs baseline: 20.2476x; 20.2476x over previous
//
#include <hip/hip_runtime.h>
#include <hip/hip_bf16.h>
#include <stdint.h>

// ESN: out[t] = tanh(U[t] + W_res @ s_{t-1}), T=16384 sequential steps.
// Kernel 1: U = X@W_in^T into d_out in place.
// Kernel 2: 8 persistent blocks x 1024 threads. Round-2-proven exchange:
// tagged (tag<<32|value) slots in d_ws, agent-scope stores/loads (LLC),
// COALESCED poll (each thread owns exactly one slot), LDS broadcast, one
// barrier per step, depth-2 ping-pong. Sparse W_res rows in registers.
// r4 lesson: scattered per-gather polls melt the fabric; polls must be
// coalesced and gathers served from LDS.

constexpr int T_N = 16384;
constexpr int R_N = 1024;
constexpr int I_N = 128;

// ---------------------------------------------------------------- kernel 1
constexpr int BT = 64, BR = 64;

__global__ __launch_bounds__(256) void gemm_u_kernel(
    const float* __restrict__ X, const float* __restrict__ Win,
    float* __restrict__ U)
{
    __shared__ float XS[BT][68];
    __shared__ float WS[BR][68];
    const int tid = threadIdx.x;
    const int ty = tid >> 4, tx = tid & 15;
    const int t0 = blockIdx.x * BT;
    const int r0 = blockIdx.y * BR;
    float acc[4][4] = {};

    for (int k0 = 0; k0 < I_N; k0 += 64) {
        for (int idx = tid; idx < BT * 16; idx += 256) {
            int row = idx >> 4, c4 = (idx & 15) << 2;
            *reinterpret_cast<float4*>(&XS[row][c4]) =
                *reinterpret_cast<const float4*>(&X[(size_t)(t0 + row) * I_N + k0 + c4]);
        }
        for (int idx = tid; idx < BR * 16; idx += 256) {
            int row = idx >> 4, c4 = (idx & 15) << 2;
            *reinterpret_cast<float4*>(&WS[row][c4]) =
                *reinterpret_cast<const float4*>(&Win[(size_t)(r0 + row) * I_N + k0 + c4]);
        }
        __syncthreads();
#pragma unroll
        for (int k = 0; k < 64; k += 4) {
            float4 a[4], b[4];
#pragma unroll
            for (int i = 0; i < 4; ++i)
                a[i] = *reinterpret_cast<const float4*>(&XS[ty + 16 * i][k]);
#pragma unroll
            for (int jj = 0; jj < 4; ++jj)
                b[jj] = *reinterpret_cast<const float4*>(&WS[tx + 16 * jj][k]);
#pragma unroll
            for (int i = 0; i < 4; ++i)
#pragma unroll
                for (int jj = 0; jj < 4; ++jj)
                    acc[i][jj] += a[i].x * b[jj].x + a[i].y * b[jj].y +
                                  a[i].z * b[jj].z + a[i].w * b[jj].w;
        }
        __syncthreads();
    }
#pragma unroll
    for (int i = 0; i < 4; ++i)
#pragma unroll
        for (int jj = 0; jj < 4; ++jj)
            U[(size_t)(t0 + ty + 16 * i) * R_N + (r0 + tx + 16 * jj)] = acc[i][jj];
}

// ---------------------------------------------------------------- kernel 2
constexpr int GBLK  = 8;              // persistent blocks
constexpr int B2    = 1024;           // threads/block == R_N: 1 poll slot each
constexpr int RPB   = R_N / GBLK;     // 128 rows per block
constexpr int TPR   = 8;              // threads per row
constexpr int KMAX  = 96;             // nnz/row cap (validated r1/r2/r4)
constexpr int NSL   = KMAX / TPR;     // 12 register slots per thread
constexpr int DEPTH = 2;              // ping-pong (barrier/step makes it safe)
constexpr int PCAP  = 1 << 20;        // anti-hang poll cap

typedef unsigned long long ull;

__device__ __forceinline__ float fast_tanh(float x) {
    float ax = fabsf(x);
    float e  = __expf(-2.0f * ax);
    float y  = (1.0f - e) / (1.0f + e);
    return copysignf(y, x);
}

__global__ __launch_bounds__(1024) void esn_scan_kernel(
    const float* __restrict__ Wres, const float* __restrict__ state0,
    float* out, ull* slots)
{
    __shared__ float sbuf[DEPTH][R_N];    // 8 KB: broadcast state
    __shared__ uint2 ell[RPB][KMAX];      // 98 KB: (col, val-bits)
    __shared__ int   cnt[RPB];

    const int tid  = threadIdx.x;
    const int b    = blockIdx.x;
    const int row0 = b * RPB;

    // ---- one-time: extract this block's sparse rows from dense W_res
    if (tid < RPB) cnt[tid] = 0;
    __syncthreads();
    for (int idx = tid; idx < RPB * R_N; idx += B2) {    // coalesced scan
        int r = idx >> 10, c = idx & (R_N - 1);
        float w = Wres[(size_t)(row0 + r) * R_N + c];
        if (w != 0.0f) {
            int slot = atomicAdd(&cnt[r], 1);
            if (slot < KMAX) ell[r][slot] = make_uint2((uint32_t)c, __float_as_uint(w));
        }
    }
    __syncthreads();

    // ---- hoist my slots into registers (dead slots: col=0, val=0)
    const int rloc = tid / TPR;           // 0..127
    const int j    = tid % TPR;           // 0..7
    const int row  = row0 + rloc;
    int   cols[NSL];
    float vals[NSL];
    {
        int myn = cnt[rloc];
#pragma unroll
        for (int k = 0; k < NSL; ++k) {
            int slot = j + k * TPR;
            if (slot < myn) {
                uint2 e = ell[rloc][slot];
                cols[k] = (int)e.x;
                vals[k] = __uint_as_float(e.y);
            } else { cols[k] = 0; vals[k] = 0.0f; }
        }
    }

    // seed parity-1 (= (-1)&1) with state0; step t gathers sbuf[(t-1)&1]
    sbuf[1][tid] = state0[tid];

    float u_cur = (j == 0) ? out[row] : 0.0f;   // u_0 for my row
    __syncthreads();

    // ---- the sequential scan: coalesced poll -> LDS -> barrier -> gather
    for (int t = 0; t < T_N; ++t) {
        const int p = (t - 1) & 1;            // parity holding s_{t-1}

        // prefetch next u early (same thread overwrites that slot at t+1)
        float u_next = 0.0f;
        if (j == 0 && t + 1 < T_N) u_next = out[(size_t)(t + 1) * R_N + row];

        if (t > 0) {
            // poll MY slot (thread tid <-> state element tid): coalesced
            const ull* addr = slots + ((size_t)p << 10) + tid;
            const uint32_t want = (uint32_t)t;    // s_{t-1} carries tag t
            ull w;
            int rounds = 0;
            do {
                w = __hip_atomic_load(addr, __ATOMIC_RELAXED,
                                      __HIP_MEMORY_SCOPE_AGENT);
            } while ((uint32_t)(w >> 32) < want && ++rounds < PCAP);
            sbuf[p][tid] = __uint_as_float((uint32_t)w);
        }
        __syncthreads();                       // sbuf[p] complete

        float acc = 0.0f;
#pragma unroll
        for (int k = 0; k < NSL; ++k) acc += vals[k] * sbuf[p][cols[k]];

        acc += __shfl_xor(acc, 1, TPR);
        acc += __shfl_xor(acc, 2, TPR);
        acc += __shfl_xor(acc, 4, TPR);

        if (j == 0) {
            float y = fast_tanh(u_cur + acc);
            // publish FIRST (consumers wait on this), answer second
            ull pkt = ((ull)(uint32_t)(t + 1) << 32) | (ull)__float_as_uint(y);
            __hip_atomic_store(&slots[((size_t)(t & 1) << 10) + row], pkt,
                               __ATOMIC_RELAXED, __HIP_MEMORY_SCOPE_AGENT);
            out[(size_t)t * R_N + row] = y;
        }
        u_cur = u_next;
        // no trailing barrier needed: next step's sbuf write targets the
        // other parity, and its overwrite of THIS parity only happens at
        // t+2 after barrier(t+1), which follows every step-t gather.
    }
}

// ---------------------------------------------------------------- launcher
extern "C" void kernel_launch(void* const* d_in, const int* in_sizes, int n_in,
                              void* d_out, int out_size, void* d_ws, size_t ws_size,
                              hipStream_t stream)
{
    const float* X      = (const float*)d_in[0];   // (T, I)
    const float* W_in   = (const float*)d_in[1];   // (R, I)
    const float* W_res  = (const float*)d_in[2];   // (R, R)
    const float* state0 = (const float*)d_in[3];   // (R,)
    float* out = (float*)d_out;                    // (T, R)
    ull* slots = (ull*)d_ws;                       // DEPTH x 1024 tagged slots

    // tags must start < 1 every launch (harness poisons ws with 0xAA)
    hipMemsetAsync(d_ws, 0, (size_t)DEPTH * R_N * sizeof(ull), stream);

    dim3 g1(T_N / BT, R_N / BR);
    gemm_u_kernel<<<g1, 256, 0, stream>>>(X, W_in, out);

    esn_scan_kernel<<<GBLK, B2, 0, stream>>>(W_res, state0, out, slots);
}

// Round 6
// 24163.023 us; speedup vs baseline: 20.3369x; 1.0044x over previous
//
#include <hip/hip_runtime.h>
#include <hip/hip_bf16.h>
#include <stdint.h>

// ESN: out[t] = tanh(U[t] + W_res @ s_{t-1}), T=16384 sequential steps.
// Kernel 1: U = X@W_in^T into d_out in place.
// Kernel 2: 8 worker blocks x 1024 threads claimed on ONE XCD (XCC_ID
// pigeonhole over 64 blocks; claim mechanism proven in r4). Exchange:
// 4-byte packets (24-bit rounded value | 8-bit tag), producer agent-scope
// store (write-through: fresh at local L2 AND LLC), consumer polls own slot
// coalesced. Fast path: SE-scope atomic-add-0 at the shared L2 — enabled
// only after a runtime co-L2 probe proves all 8 workers share the producer's
// L2 (plain dirty-line store visible to SE atomics <=> same L2, since L2s
// are non-coherent writeback). Otherwise/fallback: agent loads (r5-proven).
// Gather: compacted ELL loop (skip dead slots) to cut LDS-pipe time.

constexpr int T_N = 16384;
constexpr int R_N = 1024;
constexpr int I_N = 128;

// ---------------------------------------------------------------- kernel 1
constexpr int BT = 64, BR = 64;

__global__ __launch_bounds__(256) void gemm_u_kernel(
    const float* __restrict__ X, const float* __restrict__ Win,
    float* __restrict__ U)
{
    __shared__ float XS[BT][68];
    __shared__ float WS[BR][68];
    const int tid = threadIdx.x;
    const int ty = tid >> 4, tx = tid & 15;
    const int t0 = blockIdx.x * BT;
    const int r0 = blockIdx.y * BR;
    float acc[4][4] = {};

    for (int k0 = 0; k0 < I_N; k0 += 64) {
        for (int idx = tid; idx < BT * 16; idx += 256) {
            int row = idx >> 4, c4 = (idx & 15) << 2;
            *reinterpret_cast<float4*>(&XS[row][c4]) =
                *reinterpret_cast<const float4*>(&X[(size_t)(t0 + row) * I_N + k0 + c4]);
        }
        for (int idx = tid; idx < BR * 16; idx += 256) {
            int row = idx >> 4, c4 = (idx & 15) << 2;
            *reinterpret_cast<float4*>(&WS[row][c4]) =
                *reinterpret_cast<const float4*>(&Win[(size_t)(r0 + row) * I_N + k0 + c4]);
        }
        __syncthreads();
#pragma unroll
        for (int k = 0; k < 64; k += 4) {
            float4 a[4], b[4];
#pragma unroll
            for (int i = 0; i < 4; ++i)
                a[i] = *reinterpret_cast<const float4*>(&XS[ty + 16 * i][k]);
#pragma unroll
            for (int jj = 0; jj < 4; ++jj)
                b[jj] = *reinterpret_cast<const float4*>(&WS[tx + 16 * jj][k]);
#pragma unroll
            for (int i = 0; i < 4; ++i)
#pragma unroll
                for (int jj = 0; jj < 4; ++jj)
                    acc[i][jj] += a[i].x * b[jj].x + a[i].y * b[jj].y +
                                  a[i].z * b[jj].z + a[i].w * b[jj].w;
        }
        __syncthreads();
    }
#pragma unroll
    for (int i = 0; i < 4; ++i)
#pragma unroll
        for (int jj = 0; jj < 4; ++jj)
            U[(size_t)(t0 + ty + 16 * i) * R_N + (r0 + tx + 16 * jj)] = acc[i][jj];
}

// ---------------------------------------------------------------- kernel 2
constexpr int GBLK    = 8;             // worker blocks (one XCD)
constexpr int NLAUNCH = 64;            // pigeonhole: some XCD collects 8
constexpr int B2      = 1024;          // 1 poll slot per thread
constexpr int RPB     = R_N / GBLK;    // 128 rows per block
constexpr int TPR     = 8;             // threads per row
constexpr int KMAX    = 96;            // nnz/row cap (validated r1..r5)
constexpr int NSL     = KMAX / TPR;    // 12 register slots per thread
constexpr int FASTCAP = 24;            // SE-atomic rounds before agent fallback
constexpr int PCAP    = 1 << 20;       // anti-hang cap

__device__ __forceinline__ float fast_tanh(float x) {
    float ax = fabsf(x);
    float e  = __expf(-2.0f * ax);
    float y  = (1.0f - e) / (1.0f + e);
    return copysignf(y, x);
}

// SE-scope atomic add 0 with return: executes at the XCD L2 (never L1-stale)
__device__ __forceinline__ uint32_t l2_atomic_read(uint32_t* addr) {
    uint32_t old;
    asm volatile("global_atomic_add %0, %1, %2, off sc0\n\t"
                 "s_waitcnt vmcnt(0)"
                 : "=v"(old) : "v"(addr), "v"(0u) : "memory");
    return old;
}

__global__ __launch_bounds__(1024) void esn_scan_kernel(
    const float* __restrict__ Wres, const float* __restrict__ state0,
    float* out, uint32_t* hdr, uint32_t* slots)
{
    __shared__ int   s_role, s_fast;
    __shared__ float sbuf[2][R_N];        // 8 KB ping-pong state
    __shared__ uint2 ell[RPB][KMAX];      // 98 KB (col, val-bits)
    __shared__ int   cnt[RPB];

    const int tid = threadIdx.x;

    // ---- claim: first XCD to collect 8 blocks wins (r4-proven mechanism)
    if (tid == 0) {
        uint32_t xcd;
        asm volatile("s_getreg_b32 %0, hwreg(HW_REG_XCC_ID)" : "=s"(xcd));
        xcd &= 7u;
        uint32_t rank = __hip_atomic_fetch_add(&hdr[xcd], 1u,
                            __ATOMIC_RELAXED, __HIP_MEMORY_SCOPE_AGENT);
        int role = -1;
        if (rank < (uint32_t)GBLK) {
            if (rank == (uint32_t)(GBLK - 1)) {
                uint32_t expected = 0u;
                __hip_atomic_compare_exchange_strong(&hdr[8], &expected, xcd + 1u,
                    __ATOMIC_RELAXED, __ATOMIC_RELAXED, __HIP_MEMORY_SCOPE_AGENT);
            }
            uint32_t win = 0; int sp = 0;
            do {
                win = __hip_atomic_load(&hdr[8], __ATOMIC_RELAXED,
                                        __HIP_MEMORY_SCOPE_AGENT);
            } while (win == 0u && ++sp < PCAP);
            if (win == xcd + 1u) role = (int)rank;
        }
        s_role = role; s_fast = 0;
    }
    __syncthreads();
    const int b = s_role;
    if (b < 0) return;
    const int row0 = b * RPB;

    // ---- co-L2 probe: rank0 dirties a line with a PLAIN store (L2-local,
    // invisible at LLC); workers poll it with SE atomics. Unanimous "seen"
    // proves shared L2 -> enable fast path. Probe address isolated.
    if (tid == 0) {
        uint32_t* test = hdr + 96;
        if (b == 0) {
            asm volatile("global_store_dword %0, %1, off"
                         :: "v"(test), "v"(0xC0FFEEu) : "memory");
            __hip_atomic_store(&hdr[9], 1u, __ATOMIC_RELAXED,
                               __HIP_MEMORY_SCOPE_AGENT);
        } else {
            int sp = 0;
            while (!__hip_atomic_load(&hdr[9], __ATOMIC_RELAXED,
                                      __HIP_MEMORY_SCOPE_AGENT) && ++sp < PCAP) {}
        }
        uint32_t seen = 0;
        for (int r = 0; r < 32 && !seen; ++r)
            if (l2_atomic_read(test) == 0xC0FFEEu) seen = 1;
        __hip_atomic_store(&hdr[16 + b], seen ? 1u : 2u,
                           __ATOMIC_RELAXED, __HIP_MEMORY_SCOPE_AGENT);
        uint32_t ok = 1;
        for (int i = 0; i < GBLK; ++i) {
            uint32_t v; int sp = 0;
            do { v = __hip_atomic_load(&hdr[16 + i], __ATOMIC_RELAXED,
                                       __HIP_MEMORY_SCOPE_AGENT);
            } while (!v && ++sp < PCAP);
            if (v != 1u) ok = 0;
        }
        s_fast = (int)ok;
    }
    __syncthreads();
    const bool fastp = (s_fast != 0);

    // ---- one-time: extract this block's sparse rows from dense W_res
    if (tid < RPB) cnt[tid] = 0;
    __syncthreads();
    for (int idx = tid; idx < RPB * R_N; idx += B2) {     // coalesced scan
        int r = idx >> 10, c = idx & (R_N - 1);
        float w = Wres[(size_t)(row0 + r) * R_N + c];
        if (w != 0.0f) {
            int slot = atomicAdd(&cnt[r], 1);
            if (slot < KMAX) ell[r][slot] = make_uint2((uint32_t)c, __float_as_uint(w));
        }
    }
    __syncthreads();

    // ---- hoist my slots into registers; compact loop bound kcnt
    const int rloc = tid / TPR;           // 0..127
    const int j    = tid % TPR;           // 0..7
    const int row  = row0 + rloc;
    int   cols[NSL];
    float vals[NSL];
    int   kcnt;
    {
        int myn = cnt[rloc];
        if (myn > KMAX) myn = KMAX;
        kcnt = (myn > j) ? (((myn - 1 - j) >> 3) + 1) : 0;
#pragma unroll
        for (int k = 0; k < NSL; ++k) {
            int slot = j + k * TPR;
            if (slot < myn) {
                uint2 e = ell[rloc][slot];
                cols[k] = (int)e.x;
                vals[k] = __uint_as_float(e.y);
            } else { cols[k] = 0; vals[k] = 0.0f; }
        }
    }

    sbuf[1][tid] = state0[tid];                   // seed parity (t-1)&1 @ t=0
    float u_cur = (j == 0) ? out[row] : 0.0f;
    __syncthreads();

    // ---- sequential scan: coalesced poll -> LDS -> barrier -> gather
    for (int t = 0; t < T_N; ++t) {
        const int p = (t - 1) & 1;

        float u_next = 0.0f;
        if (j == 0 && t + 1 < T_N) u_next = out[(size_t)(t + 1) * R_N + row];

        if (t > 0) {
            uint32_t* addr = slots + ((size_t)p << 10) + tid;
            const uint32_t want8 = (uint32_t)(t & 0xFF);  // s_{t-1} tag
            uint32_t w = 0;
            bool got = false;
            if (fastp) {                       // L2-served poll (proven co-L2)
                for (int r = 0; r < FASTCAP; ++r) {
                    w = l2_atomic_read(addr);
                    if ((w & 0xFFu) == want8) { got = true; break; }
                }
            }
            if (!got) {                        // agent scope (LLC, r5-proven)
                int sp = 0;
                do {
                    w = __hip_atomic_load(addr, __ATOMIC_RELAXED,
                                          __HIP_MEMORY_SCOPE_AGENT);
                } while ((w & 0xFFu) != want8 && ++sp < PCAP);
            }
            sbuf[p][tid] = __uint_as_float(w & 0xFFFFFF00u);
        }
        __syncthreads();                       // sbuf[p] complete

        float acc = 0.0f;
#pragma unroll
        for (int k = 0; k < NSL; ++k)
            if (k < kcnt) acc += vals[k] * sbuf[p][cols[k]];

        acc += __shfl_xor(acc, 1, TPR);
        acc += __shfl_xor(acc, 2, TPR);
        acc += __shfl_xor(acc, 4, TPR);

        if (j == 0) {
            float y = fast_tanh(u_cur + acc);
            uint32_t bits = __float_as_uint(y);
            uint32_t pkt  = ((bits + 0x80u) & 0xFFFFFF00u)   // round to 24b
                          | ((uint32_t)(t + 1) & 0xFFu);
            __hip_atomic_store(&slots[((size_t)(t & 1) << 10) + row], pkt,
                               __ATOMIC_RELAXED, __HIP_MEMORY_SCOPE_AGENT);
            out[(size_t)t * R_N + row] = y;
        }
        u_cur = u_next;
        // next step's sbuf write targets the other parity; this parity is
        // only overwritten at t+2, after barrier(t+1) which follows every
        // step-t gather -> safe without a trailing barrier.
    }
}

// ---------------------------------------------------------------- launcher
extern "C" void kernel_launch(void* const* d_in, const int* in_sizes, int n_in,
                              void* d_out, int out_size, void* d_ws, size_t ws_size,
                              hipStream_t stream)
{
    const float* X      = (const float*)d_in[0];   // (T, I)
    const float* W_in   = (const float*)d_in[1];   // (R, I)
    const float* W_res  = (const float*)d_in[2];   // (R, R)
    const float* state0 = (const float*)d_in[3];   // (R,)
    float* out = (float*)d_out;                    // (T, R)

    uint32_t* hdr   = (uint32_t*)d_ws;                     // 1 KB header
    uint32_t* slots = (uint32_t*)((char*)d_ws + 1024);     // 2 x 1024 x 4B

    // zero header + ring tags (harness poisons ws with 0xAA each launch)
    hipMemsetAsync(d_ws, 0, 1024 + (size_t)2 * R_N * sizeof(uint32_t), stream);

    dim3 g1(T_N / BT, R_N / BR);
    gemm_u_kernel<<<g1, 256, 0, stream>>>(X, W_in, out);

    esn_scan_kernel<<<NLAUNCH, B2, 0, stream>>>(W_res, state0, out, hdr, slots);
}